// Round 1
// baseline (444.354 us; speedup 1.0000x reference)
//
#include <hip/hip_runtime.h>
#include <hip/hip_fp16.h>

#define NN 20000
#define DD 128
#define EE 640000
#define TSEQ 12
#define CAP 128          // per-node CSR bucket capacity (Poisson(32), 11 sigma)
#define PADI 32          // counter padding: one counter per 128-byte line

__device__ __forceinline__ void fma4(float4& acc, float a, const float4& w) {
  acc.x += a * w.x; acc.y += a * w.y; acc.z += a * w.z; acc.w += a * w.w;
}

__device__ __forceinline__ float4 h8_to_f4(uint2 v) {
  union { unsigned u; __half2 h; } a, b;
  a.u = v.x; b.u = v.y;
  float2 fa = __half22float2(a.h);
  float2 fb = __half22float2(b.h);
  return make_float4(fa.x, fa.y, fb.x, fb.y);
}

__device__ __forceinline__ uint2 f4_to_h8(float4 o) {
  union { unsigned u; __half2 h; } a, b;
  a.h = __floats2half2_rn(o.x, o.y);
  b.h = __floats2half2_rn(o.z, o.w);
  uint2 r; r.x = a.u; r.y = b.u;
  return r;
}

// ---------------- prep: zero padded counters + all weight transposes ----------------
// blocks [0,625): deg_pad init (1.0 at slot 0 of each line, else 0)
// blocks [625,1250): cnt_pad zero
// blocks [1250,1634): transposes
__global__ void k_prep(const float* __restrict__ fuse_W,
                       const float* __restrict__ gcn_W,
                       float* __restrict__ deg_pad, int* __restrict__ cnt_pad,
                       float* __restrict__ fuse_Wt,
                       float* __restrict__ gWt0,
                       __half* __restrict__ gWh) {
  int b = blockIdx.x;
  if (b < 625) {
    int i = b * 256 + threadIdx.x;             // float4 slot; 160000 cover 640000 floats
    float4 z = make_float4((i & 7) == 0 ? 1.0f : 0.0f, 0.f, 0.f, 0.f);
    ((float4*)deg_pad)[i] = z;
  } else if (b < 1250) {
    int i = (b - 625) * 256 + threadIdx.x;
    ((int4*)cnt_pad)[i] = make_int4(0, 0, 0, 0);
  } else {
    int i = (b - 1250) * 256 + threadIdx.x;
    if (i < 49152) {
      int k = i >> 7, d = i & 127;
      fuse_Wt[i] = fuse_W[d * 384 + k];
    } else if (i < 65536) {
      int j = i - 49152;
      int k = j >> 7, d = j & 127;
      gWt0[j] = gcn_W[d * 128 + k];
    } else if (i < 98304) {
      int j = i - 65536;
      int l = 1 + (j >> 14), jj = j & 16383;
      int k = jj >> 7, d = jj & 127;
      gWh[j] = (__half)gcn_W[l * 16384 + d * 128 + k];
    }
  }
}

// ---------------- GEMM device body: out[n][d] = sum_k A[n][k]*Wt[k][d] (+bias) ------
#define G_TN 2
#define G_BN 32   // 16 dq-groups * 2 rows

__device__ __forceinline__ void gemm_body(
    float* Ws, int gb,
    const float* a0, int s0, const float* a1, int s1, const float* a2, int s2,
    int nparts, const float* Wt, const float* bias, const float* deg_pad,
    float* outf, uint2* outh)
{
  const int t = threadIdx.x;
  const int dq = t & 15;
  const int ng = t >> 4;
  const int n_base = gb * G_BN + ng * G_TN;

  float4 acc0[G_TN], acc1[G_TN];
  #pragma unroll
  for (int i = 0; i < G_TN; ++i) {
    acc0[i] = make_float4(0.f, 0.f, 0.f, 0.f);
    acc1[i] = make_float4(0.f, 0.f, 0.f, 0.f);
  }

  for (int p = 0; p < nparts; ++p) {
    const float* ap; int as;
    if (p == 0) { ap = a0; as = s0; }
    else if (p == 1) { ap = a1; as = s1; }
    else { ap = a2; as = s2; }
    const float* rp[G_TN];
    #pragma unroll
    for (int i = 0; i < G_TN; ++i) rp[i] = ap + (size_t)(n_base + i) * as;

    for (int c = 0; c < 2; ++c) {
      const float4* wsrc = (const float4*)(Wt + (p * 128 + c * 64) * 128);
      float4* wdst = (float4*)Ws;
      #pragma unroll
      for (int it = 0; it < 8; ++it) wdst[it * 256 + t] = wsrc[it * 256 + t];
      __syncthreads();

      const int ks = c * 64;
      for (int k = 0; k < 64; k += 4) {
        float4 av[G_TN];
        #pragma unroll
        for (int i = 0; i < G_TN; ++i) av[i] = *(const float4*)(rp[i] + ks + k);
        #pragma unroll
        for (int j = 0; j < 4; ++j) {
          const float4 w0 = *(const float4*)&Ws[(k + j) * 128 + 4 * dq];
          const float4 w1 = *(const float4*)&Ws[(k + j) * 128 + 64 + 4 * dq];
          #pragma unroll
          for (int i = 0; i < G_TN; ++i) {
            float a = (j == 0) ? av[i].x : (j == 1) ? av[i].y : (j == 2) ? av[i].z : av[i].w;
            fma4(acc0[i], a, w0);
            fma4(acc1[i], a, w1);
          }
        }
      }
      __syncthreads();
    }
  }

  float4 b0 = make_float4(0.f,0.f,0.f,0.f), b1 = b0;
  if (bias) {
    b0 = *(const float4*)&bias[4 * dq];
    b1 = *(const float4*)&bias[64 + 4 * dq];
  }
  #pragma unroll
  for (int i = 0; i < G_TN; ++i) {
    int r = n_base + i;
    float4 o0 = make_float4(acc0[i].x + b0.x, acc0[i].y + b0.y,
                            acc0[i].z + b0.z, acc0[i].w + b0.w);
    float4 o1 = make_float4(acc1[i].x + b1.x, acc1[i].y + b1.y,
                            acc1[i].z + b1.z, acc1[i].w + b1.w);
    if (outf) {
      *(float4*)(outf + (size_t)r * DD + 4 * dq) = o0;
      *(float4*)(outf + (size_t)r * DD + 64 + 4 * dq) = o1;
    } else {
      float di = rsqrtf(deg_pad[(size_t)r * PADI]);
      o0.x *= di; o0.y *= di; o0.z *= di; o0.w *= di;
      o1.x *= di; o1.y *= di; o1.z *= di; o1.w *= di;
      outh[(size_t)r * 32 + dq] = f4_to_h8(o0);
      outh[(size_t)r * 32 + 16 + dq] = f4_to_h8(o1);
    }
  }
}

// ---------------- mega: even blocks = fuse-GEMM, odd blocks = edges (ILP-4) ----------
// grid 1250: even b -> GEMM tile b>>1 (625 tiles); odd b -> edge chunk b>>1
// (625 chunks x 1024 edges, 4 edges/thread via int4/float4 vector loads).
// Interleaving by parity keeps latency-bound edge chains resident alongside
// the VALU-bound GEMM blocks across the whole kernel instead of back-loading
// 2500 single-edge-per-thread blocks.
__global__ __launch_bounds__(256, 4) void k_mega(
    const float* __restrict__ emb, const float* __restrict__ demand,
    const float* __restrict__ supply,
    const float* __restrict__ fuse_Wt, const float* __restrict__ fuse_b,
    float* __restrict__ temp0,
    const int* __restrict__ src, const int* __restrict__ dst,
    const float* __restrict__ w,
    float* __restrict__ deg_pad, int* __restrict__ cnt_pad,
    uint2* __restrict__ csr)
{
  __shared__ float Ws[64 * 128];    // 32 KB (edge blocks carry it unused)
  if ((blockIdx.x & 1) == 0) {
    gemm_body(Ws, blockIdx.x >> 1,
              emb, 128, demand + 11 * 128, TSEQ * 128, supply + 11 * 128, TSEQ * 128,
              3, fuse_Wt, fuse_b, nullptr, temp0, nullptr);
  } else {
    // 4 edges per thread: int4-vectorized loads, 4 independent atomic chains
    int i = (int)(blockIdx.x >> 1) * 256 + threadIdx.x;   // int4 index, 160000 total
    const int4  s4 = ((const int4*)src)[i];
    const int4  d4 = ((const int4*)dst)[i];
    const float4 w4 = ((const float4*)w)[i];

    // fire-and-forget degree accumulation (no return dependency)
    atomicAdd(&deg_pad[(size_t)d4.x * PADI], w4.x);
    atomicAdd(&deg_pad[(size_t)d4.y * PADI], w4.y);
    atomicAdd(&deg_pad[(size_t)d4.z * PADI], w4.z);
    atomicAdd(&deg_pad[(size_t)d4.w * PADI], w4.w);

    // 4 independent slot-claim round trips in flight per lane
    int sl0 = atomicAdd(&cnt_pad[(size_t)d4.x * PADI], 1);
    int sl1 = atomicAdd(&cnt_pad[(size_t)d4.y * PADI], 1);
    int sl2 = atomicAdd(&cnt_pad[(size_t)d4.z * PADI], 1);
    int sl3 = atomicAdd(&cnt_pad[(size_t)d4.w * PADI], 1);

    if (sl0 < CAP) csr[(size_t)d4.x * CAP + sl0] = make_uint2((unsigned)s4.x, __float_as_uint(w4.x));
    if (sl1 < CAP) csr[(size_t)d4.y * CAP + sl1] = make_uint2((unsigned)s4.y, __float_as_uint(w4.y));
    if (sl2 < CAP) csr[(size_t)d4.z * CAP + sl2] = make_uint2((unsigned)s4.z, __float_as_uint(w4.z));
    if (sl3 < CAP) csr[(size_t)d4.w * CAP + sl3] = make_uint2((unsigned)s4.w, __float_as_uint(w4.w));
  }
}

// ---------------- x0 GEMM: xh = rsqrt(deg)*(temp0 @ W0^T), fp16 ----------------
__global__ __launch_bounds__(256, 4) void k_gemm_x0(
    const float* __restrict__ temp0, const float* __restrict__ gWt0,
    const float* __restrict__ deg_pad, uint2* __restrict__ outh)
{
  __shared__ float Ws[64 * 128];
  gemm_body(Ws, blockIdx.x, temp0, 128, temp0, 128, temp0, 128,
            1, gWt0, nullptr, deg_pad, nullptr, outh);
}

// ---------------- fused aggregation (+ optional next-layer GEMM) ----------------
template<bool NEXT>
__global__ __launch_bounds__(256, 4) void k_agg_fused(
    const uint2* __restrict__ xh, const float* __restrict__ tin,
    const int* __restrict__ cnt_pad, const uint2* __restrict__ csr,
    const float* __restrict__ deg_pad, const float* __restrict__ bias,
    const uint2* __restrict__ Wh,      // fp16-packed next W, k-major [128][32 uint2]
    float* __restrict__ tout,
    uint2* __restrict__ xh_out)
{
  __shared__ float rows[NEXT ? 8 * 128 : 8];
  __shared__ uint2 Whs[NEXT ? 4096 : 8];

  const int t = threadIdx.x;
  const int dq = t & 31;          // uint2 column (4 dims)
  const int nl = t >> 5;          // 8 nodes per block
  const int n = blockIdx.x * 8 + nl;

  uint2 wreg[16];
  if constexpr (NEXT) {
    #pragma unroll
    for (int i = 0; i < 16; ++i) wreg[i] = Wh[i * 256 + t];
  }

  const float di = rsqrtf(deg_pad[(size_t)n * PADI]);
  float4 acc = h8_to_f4(xh[(size_t)n * 32 + dq]);   // self loop (weight 1, pre-di)

  const size_t base = (size_t)n * CAP;
  int m = cnt_pad[(size_t)n * PADI]; if (m > CAP) m = CAP;
  int j = 0;
  for (; j + 16 <= m; j += 16) {
    uint2 c[16];
    #pragma unroll
    for (int u = 0; u < 16; ++u) c[u] = csr[base + j + u];
    uint2 v[16];
    #pragma unroll
    for (int u = 0; u < 16; ++u) v[u] = xh[(size_t)c[u].x * 32 + dq];
    #pragma unroll
    for (int u = 0; u < 16; ++u) fma4(acc, __uint_as_float(c[u].y), h8_to_f4(v[u]));
  }
  for (; j + 4 <= m; j += 4) {
    uint2 c[4];
    #pragma unroll
    for (int u = 0; u < 4; ++u) c[u] = csr[base + j + u];
    uint2 v[4];
    #pragma unroll
    for (int u = 0; u < 4; ++u) v[u] = xh[(size_t)c[u].x * 32 + dq];
    #pragma unroll
    for (int u = 0; u < 4; ++u) fma4(acc, __uint_as_float(c[u].y), h8_to_f4(v[u]));
  }
  for (; j < m; ++j) {
    uint2 c = csr[base + j];
    fma4(acc, __uint_as_float(c.y), h8_to_f4(xh[(size_t)c.x * 32 + dq]));
  }

  const float4 b4 = *(const float4*)&bias[4 * dq];
  const float4 ti = ((const float4*)tin)[(size_t)n * 32 + dq];
  float4 o;
  o.x = 0.9f * (di * acc.x + b4.x) + 0.1f * ti.x;
  o.y = 0.9f * (di * acc.y + b4.y) + 0.1f * ti.y;
  o.z = 0.9f * (di * acc.z + b4.z) + 0.1f * ti.z;
  o.w = 0.9f * (di * acc.w + b4.w) + 0.1f * ti.w;
  ((float4*)tout)[(size_t)n * 32 + dq] = o;

  if constexpr (NEXT) {
    #pragma unroll
    for (int i = 0; i < 16; ++i) Whs[i * 256 + t] = wreg[i];
    *(float4*)&rows[nl * 128 + 4 * dq] = o;
    __syncthreads();

    float4 x = make_float4(0.f, 0.f, 0.f, 0.f);
    const float* myrow = &rows[nl * 128];
    #pragma unroll 4
    for (int k = 0; k < 128; ++k) {
      fma4(x, myrow[k], h8_to_f4(Whs[k * 32 + dq]));
    }
    x.x *= di; x.y *= di; x.z *= di; x.w *= di;
    xh_out[(size_t)n * 32 + dq] = f4_to_h8(x);
  }
}

// ---------------- launch ----------------
extern "C" void kernel_launch(void* const* d_in, const int* in_sizes, int n_in,
                              void* d_out, int out_size, void* d_ws, size_t ws_size,
                              hipStream_t stream) {
  const float* demand = (const float*)d_in[0];
  const float* supply = (const float*)d_in[1];
  const int*   eidx   = (const int*)d_in[5];
  const float* eattr  = (const float*)d_in[6];
  const float* emb    = (const float*)d_in[10];
  const float* fuse_W = (const float*)d_in[11];
  const float* fuse_b = (const float*)d_in[12];
  const float* gcn_W  = (const float*)d_in[13];
  const float* gcn_b  = (const float*)d_in[14];
  float* outp = (float*)d_out;

  char* ws = (char*)d_ws;
  size_t o = 0;
  auto alloc = [&](size_t bytes) {
    char* p = ws + o;
    o += (bytes + 255) & ~(size_t)255;
    return p;
  };
  float*  deg_pad = (float*)alloc((size_t)NN * PADI * 4);   // 2.56 MB
  int*    cnt_pad = (int*)alloc((size_t)NN * PADI * 4);     // 2.56 MB
  uint2*  csr     = (uint2*)alloc((size_t)NN * CAP * 8);
  float*  fuse_Wt = (float*)alloc((size_t)384 * 128 * 4);
  float*  gWt0    = (float*)alloc((size_t)128 * 128 * 4);
  __half* gWh     = (__half*)alloc((size_t)2 * 128 * 128 * 2);
  float*  temp0   = (float*)alloc((size_t)NN * DD * 4);
  float*  temp1   = (float*)alloc((size_t)NN * DD * 4);
  uint2*  xh_a    = (uint2*)alloc((size_t)NN * DD * 2);
  uint2*  xh_b    = (uint2*)alloc((size_t)NN * DD * 2);

  const int* srcv = eidx;        // edge_index[0]
  const int* dstv = eidx + EE;   // edge_index[1]

  k_prep<<<1634, 256, 0, stream>>>(fuse_W, gcn_W, deg_pad, cnt_pad, fuse_Wt, gWt0, gWh);

  k_mega<<<1250, 256, 0, stream>>>(emb, demand, supply, fuse_Wt, fuse_b, temp0,
                                   srcv, dstv, eattr, deg_pad, cnt_pad, csr);

  k_gemm_x0<<<625, 256, 0, stream>>>(temp0, gWt0, deg_pad, xh_a);

  const int AB = NN / 8;  // 2500
  k_agg_fused<true ><<<AB, 256, 0, stream>>>(xh_a, temp0, cnt_pad, csr, deg_pad, gcn_b,
                                             (const uint2*)gWh, temp1, xh_b);
  k_agg_fused<true ><<<AB, 256, 0, stream>>>(xh_b, temp1, cnt_pad, csr, deg_pad, gcn_b + 128,
                                             (const uint2*)(gWh + 16384), temp0, xh_a);
  k_agg_fused<false><<<AB, 256, 0, stream>>>(xh_a, temp0, cnt_pad, csr, deg_pad, gcn_b + 256,
                                             nullptr, outp, nullptr);
}

// Round 2
// 440.582 us; speedup vs baseline: 1.0086x; 1.0086x over previous
//
#include <hip/hip_runtime.h>
#include <hip/hip_fp16.h>

#define NN 20000
#define DD 128
#define EE 640000
#define TSEQ 12
#define CAP 128          // per-node CSR bucket capacity (Poisson(32), 11 sigma)
#define PADI 32          // counter padding: one counter per 128-byte line

__device__ __forceinline__ void fma4(float4& acc, float a, const float4& w) {
  acc.x += a * w.x; acc.y += a * w.y; acc.z += a * w.z; acc.w += a * w.w;
}

__device__ __forceinline__ float4 h8_to_f4(uint2 v) {
  union { unsigned u; __half2 h; } a, b;
  a.u = v.x; b.u = v.y;
  float2 fa = __half22float2(a.h);
  float2 fb = __half22float2(b.h);
  return make_float4(fa.x, fa.y, fb.x, fb.y);
}

__device__ __forceinline__ uint2 f4_to_h8(float4 o) {
  union { unsigned u; __half2 h; } a, b;
  a.h = __floats2half2_rn(o.x, o.y);
  b.h = __floats2half2_rn(o.z, o.w);
  uint2 r; r.x = a.u; r.y = b.u;
  return r;
}

// ---------------- prep: zero padded counters + all weight transposes ----------------
__global__ void k_prep(const float* __restrict__ fuse_W,
                       const float* __restrict__ gcn_W,
                       float* __restrict__ deg_pad, int* __restrict__ cnt_pad,
                       float* __restrict__ fuse_Wt,
                       float* __restrict__ gWt0,
                       __half* __restrict__ gWh) {
  int b = blockIdx.x;
  if (b < 625) {
    int i = b * 256 + threadIdx.x;
    float4 z = make_float4((i & 7) == 0 ? 1.0f : 0.0f, 0.f, 0.f, 0.f);
    ((float4*)deg_pad)[i] = z;
  } else if (b < 1250) {
    int i = (b - 625) * 256 + threadIdx.x;
    ((int4*)cnt_pad)[i] = make_int4(0, 0, 0, 0);
  } else {
    int i = (b - 1250) * 256 + threadIdx.x;
    if (i < 49152) {
      int k = i >> 7, d = i & 127;
      fuse_Wt[i] = fuse_W[d * 384 + k];
    } else if (i < 65536) {
      int j = i - 49152;
      int k = j >> 7, d = j & 127;
      gWt0[j] = gcn_W[d * 128 + k];
    } else if (i < 98304) {
      int j = i - 65536;
      int l = 1 + (j >> 14), jj = j & 16383;
      int k = jj >> 7, d = jj & 127;
      gWh[j] = (__half)gcn_W[l * 16384 + d * 128 + k];
    }
  }
}

// ---------------- GEMM device body: out[n][d] = sum_k A[n][k]*Wt[k][d] (+bias) ------
// Staging tile is 32 k-rows x 128 d (16 KB) so 8 blocks/CU fit (128 KB LDS).
#define G_TN 2
#define G_BN 32   // 16 dq-groups * 2 rows

__device__ __forceinline__ void gemm_body(
    float* Ws, int gb,
    const float* a0, int s0, const float* a1, int s1, const float* a2, int s2,
    int nparts, const float* Wt, const float* bias, const float* deg_pad,
    float* outf, uint2* outh)
{
  const int t = threadIdx.x;
  const int dq = t & 15;
  const int ng = t >> 4;
  const int n_base = gb * G_BN + ng * G_TN;

  float4 acc0[G_TN], acc1[G_TN];
  #pragma unroll
  for (int i = 0; i < G_TN; ++i) {
    acc0[i] = make_float4(0.f, 0.f, 0.f, 0.f);
    acc1[i] = make_float4(0.f, 0.f, 0.f, 0.f);
  }

  for (int p = 0; p < nparts; ++p) {
    const float* ap; int as;
    if (p == 0) { ap = a0; as = s0; }
    else if (p == 1) { ap = a1; as = s1; }
    else { ap = a2; as = s2; }
    const float* rp[G_TN];
    #pragma unroll
    for (int i = 0; i < G_TN; ++i) rp[i] = ap + (size_t)(n_base + i) * as;

    for (int c = 0; c < 4; ++c) {              // 4 chunks of 32 k
      const float4* wsrc = (const float4*)(Wt + (p * 128 + c * 32) * 128);
      float4* wdst = (float4*)Ws;
      #pragma unroll
      for (int it = 0; it < 4; ++it) wdst[it * 256 + t] = wsrc[it * 256 + t];
      __syncthreads();

      const int ks = c * 32;
      for (int k = 0; k < 32; k += 4) {
        float4 av[G_TN];
        #pragma unroll
        for (int i = 0; i < G_TN; ++i) av[i] = *(const float4*)(rp[i] + ks + k);
        #pragma unroll
        for (int j = 0; j < 4; ++j) {
          const float4 w0 = *(const float4*)&Ws[(k + j) * 128 + 4 * dq];
          const float4 w1 = *(const float4*)&Ws[(k + j) * 128 + 64 + 4 * dq];
          #pragma unroll
          for (int i = 0; i < G_TN; ++i) {
            float a = (j == 0) ? av[i].x : (j == 1) ? av[i].y : (j == 2) ? av[i].z : av[i].w;
            fma4(acc0[i], a, w0);
            fma4(acc1[i], a, w1);
          }
        }
      }
      __syncthreads();
    }
  }

  float4 b0 = make_float4(0.f,0.f,0.f,0.f), b1 = b0;
  if (bias) {
    b0 = *(const float4*)&bias[4 * dq];
    b1 = *(const float4*)&bias[64 + 4 * dq];
  }
  #pragma unroll
  for (int i = 0; i < G_TN; ++i) {
    int r = n_base + i;
    float4 o0 = make_float4(acc0[i].x + b0.x, acc0[i].y + b0.y,
                            acc0[i].z + b0.z, acc0[i].w + b0.w);
    float4 o1 = make_float4(acc1[i].x + b1.x, acc1[i].y + b1.y,
                            acc1[i].z + b1.z, acc1[i].w + b1.w);
    if (outf) {
      *(float4*)(outf + (size_t)r * DD + 4 * dq) = o0;
      *(float4*)(outf + (size_t)r * DD + 64 + 4 * dq) = o1;
    } else {
      float di = rsqrtf(deg_pad[(size_t)r * PADI]);
      o0.x *= di; o0.y *= di; o0.z *= di; o0.w *= di;
      o1.x *= di; o1.y *= di; o1.z *= di; o1.w *= di;
      outh[(size_t)r * 32 + dq] = f4_to_h8(o0);
      outh[(size_t)r * 32 + 16 + dq] = f4_to_h8(o1);
    }
  }
}

// ---------------- mega: fuse-GEMM blocks [0,625) || edge blocks [625,3125) ----------
// r0 layout (known-good 86 us). 16 KB Ws + launch_bounds(256,8) -> 8 blocks/CU.
__global__ __launch_bounds__(256, 8) void k_mega(
    const float* __restrict__ emb, const float* __restrict__ demand,
    const float* __restrict__ supply,
    const float* __restrict__ fuse_Wt, const float* __restrict__ fuse_b,
    float* __restrict__ temp0,
    const int* __restrict__ src, const int* __restrict__ dst,
    const float* __restrict__ w,
    float* __restrict__ deg_pad, int* __restrict__ cnt_pad,
    uint2* __restrict__ csr)
{
  __shared__ float Ws[32 * 128];    // 16 KB (edge blocks carry it unused)
  if (blockIdx.x < 625) {
    gemm_body(Ws, blockIdx.x,
              emb, 128, demand + 11 * 128, TSEQ * 128, supply + 11 * 128, TSEQ * 128,
              3, fuse_Wt, fuse_b, nullptr, temp0, nullptr);
  } else {
    int e = (blockIdx.x - 625) * 256 + threadIdx.x;   // exactly EE threads
    int s = src[e], d = dst[e];
    float we = w[e];
    atomicAdd(&deg_pad[(size_t)d * PADI], we);
    int slot = atomicAdd(&cnt_pad[(size_t)d * PADI], 1);
    if (slot < CAP) csr[(size_t)d * CAP + slot] = make_uint2((unsigned)s, __float_as_uint(we));
  }
}

// ---------------- x0 GEMM: xh = rsqrt(deg)*(temp0 @ W0^T), fp16 ----------------
__global__ __launch_bounds__(256, 8) void k_gemm_x0(
    const float* __restrict__ temp0, const float* __restrict__ gWt0,
    const float* __restrict__ deg_pad, uint2* __restrict__ outh)
{
  __shared__ float Ws[32 * 128];
  gemm_body(Ws, blockIdx.x, temp0, 128, temp0, 128, temp0, 128,
            1, gWt0, nullptr, deg_pad, nullptr, outh);
}

// ---------------- fused aggregation (+ optional next-layer GEMM) ----------------
// LDS cut 36 KB -> 20 KB (W staged in two k=64 halves) + wreg preload dropped
// -> launch_bounds(256,6): 6 blocks/CU instead of 4 for the latency-bound gather.
template<bool NEXT>
__global__ __launch_bounds__(256, 6) void k_agg_fused(
    const uint2* __restrict__ xh, const float* __restrict__ tin,
    const int* __restrict__ cnt_pad, const uint2* __restrict__ csr,
    const float* __restrict__ deg_pad, const float* __restrict__ bias,
    const uint2* __restrict__ Wh,      // fp16-packed next W, k-major [128][32 uint2]
    float* __restrict__ tout,
    uint2* __restrict__ xh_out)
{
  __shared__ float rows[NEXT ? 8 * 128 : 8];
  __shared__ uint2 Whs[NEXT ? 2048 : 8];   // 16 KB: one k=64 half of W

  const int t = threadIdx.x;
  const int dq = t & 31;          // uint2 column (4 dims)
  const int nl = t >> 5;          // 8 nodes per block
  const int n = blockIdx.x * 8 + nl;

  if constexpr (NEXT) {
    // stage first k-half early; latency hides under the gather below
    #pragma unroll
    for (int i = 0; i < 8; ++i) Whs[i * 256 + t] = Wh[i * 256 + t];
  }

  const float di = rsqrtf(deg_pad[(size_t)n * PADI]);
  float4 acc = h8_to_f4(xh[(size_t)n * 32 + dq]);   // self loop (weight 1, pre-di)

  const size_t base = (size_t)n * CAP;
  int m = cnt_pad[(size_t)n * PADI]; if (m > CAP) m = CAP;
  int j = 0;
  for (; j + 16 <= m; j += 16) {
    uint2 c[16];
    #pragma unroll
    for (int u = 0; u < 16; ++u) c[u] = csr[base + j + u];
    uint2 v[16];
    #pragma unroll
    for (int u = 0; u < 16; ++u) v[u] = xh[(size_t)c[u].x * 32 + dq];
    #pragma unroll
    for (int u = 0; u < 16; ++u) fma4(acc, __uint_as_float(c[u].y), h8_to_f4(v[u]));
  }
  for (; j + 4 <= m; j += 4) {
    uint2 c[4];
    #pragma unroll
    for (int u = 0; u < 4; ++u) c[u] = csr[base + j + u];
    uint2 v[4];
    #pragma unroll
    for (int u = 0; u < 4; ++u) v[u] = xh[(size_t)c[u].x * 32 + dq];
    #pragma unroll
    for (int u = 0; u < 4; ++u) fma4(acc, __uint_as_float(c[u].y), h8_to_f4(v[u]));
  }
  for (; j < m; ++j) {
    uint2 c = csr[base + j];
    fma4(acc, __uint_as_float(c.y), h8_to_f4(xh[(size_t)c.x * 32 + dq]));
  }

  const float4 b4 = *(const float4*)&bias[4 * dq];
  const float4 ti = ((const float4*)tin)[(size_t)n * 32 + dq];
  float4 o;
  o.x = 0.9f * (di * acc.x + b4.x) + 0.1f * ti.x;
  o.y = 0.9f * (di * acc.y + b4.y) + 0.1f * ti.y;
  o.z = 0.9f * (di * acc.z + b4.z) + 0.1f * ti.z;
  o.w = 0.9f * (di * acc.w + b4.w) + 0.1f * ti.w;
  ((float4*)tout)[(size_t)n * 32 + dq] = o;

  if constexpr (NEXT) {
    *(float4*)&rows[nl * 128 + 4 * dq] = o;
    __syncthreads();            // covers rows store + Whs half-0 staging

    float4 x = make_float4(0.f, 0.f, 0.f, 0.f);
    const float* myrow = &rows[nl * 128];
    #pragma unroll 4
    for (int k = 0; k < 64; ++k) {
      fma4(x, myrow[k], h8_to_f4(Whs[k * 32 + dq]));
    }
    __syncthreads();            // all done with half 0
    #pragma unroll
    for (int i = 0; i < 8; ++i) Whs[i * 256 + t] = Wh[2048 + i * 256 + t];
    __syncthreads();            // half 1 staged
    #pragma unroll 4
    for (int k = 0; k < 64; ++k) {
      fma4(x, myrow[64 + k], h8_to_f4(Whs[k * 32 + dq]));
    }
    x.x *= di; x.y *= di; x.z *= di; x.w *= di;
    xh_out[(size_t)n * 32 + dq] = f4_to_h8(x);
  }
}

// ---------------- launch ----------------
extern "C" void kernel_launch(void* const* d_in, const int* in_sizes, int n_in,
                              void* d_out, int out_size, void* d_ws, size_t ws_size,
                              hipStream_t stream) {
  const float* demand = (const float*)d_in[0];
  const float* supply = (const float*)d_in[1];
  const int*   eidx   = (const int*)d_in[5];
  const float* eattr  = (const float*)d_in[6];
  const float* emb    = (const float*)d_in[10];
  const float* fuse_W = (const float*)d_in[11];
  const float* fuse_b = (const float*)d_in[12];
  const float* gcn_W  = (const float*)d_in[13];
  const float* gcn_b  = (const float*)d_in[14];
  float* outp = (float*)d_out;

  char* ws = (char*)d_ws;
  size_t o = 0;
  auto alloc = [&](size_t bytes) {
    char* p = ws + o;
    o += (bytes + 255) & ~(size_t)255;
    return p;
  };
  float*  deg_pad = (float*)alloc((size_t)NN * PADI * 4);   // 2.56 MB
  int*    cnt_pad = (int*)alloc((size_t)NN * PADI * 4);     // 2.56 MB
  uint2*  csr     = (uint2*)alloc((size_t)NN * CAP * 8);
  float*  fuse_Wt = (float*)alloc((size_t)384 * 128 * 4);
  float*  gWt0    = (float*)alloc((size_t)128 * 128 * 4);
  __half* gWh     = (__half*)alloc((size_t)2 * 128 * 128 * 2);
  float*  temp0   = (float*)alloc((size_t)NN * DD * 4);
  float*  temp1   = (float*)alloc((size_t)NN * DD * 4);
  uint2*  xh_a    = (uint2*)alloc((size_t)NN * DD * 2);
  uint2*  xh_b    = (uint2*)alloc((size_t)NN * DD * 2);

  const int* srcv = eidx;        // edge_index[0]
  const int* dstv = eidx + EE;   // edge_index[1]

  k_prep<<<1634, 256, 0, stream>>>(fuse_W, gcn_W, deg_pad, cnt_pad, fuse_Wt, gWt0, gWh);

  k_mega<<<3125, 256, 0, stream>>>(emb, demand, supply, fuse_Wt, fuse_b, temp0,
                                   srcv, dstv, eattr, deg_pad, cnt_pad, csr);

  k_gemm_x0<<<625, 256, 0, stream>>>(temp0, gWt0, deg_pad, xh_a);

  const int AB = NN / 8;  // 2500
  k_agg_fused<true ><<<AB, 256, 0, stream>>>(xh_a, temp0, cnt_pad, csr, deg_pad, gcn_b,
                                             (const uint2*)gWh, temp1, xh_b);
  k_agg_fused<true ><<<AB, 256, 0, stream>>>(xh_b, temp1, cnt_pad, csr, deg_pad, gcn_b + 128,
                                             (const uint2*)(gWh + 16384), temp0, xh_a);
  k_agg_fused<false><<<AB, 256, 0, stream>>>(xh_a, temp0, cnt_pad, csr, deg_pad, gcn_b + 256,
                                             nullptr, outp, nullptr);
}

// Round 3
// 406.585 us; speedup vs baseline: 1.0929x; 1.0836x over previous
//
#include <hip/hip_runtime.h>
#include <hip/hip_fp16.h>

#define NN 20000
#define DD 128
#define EE 640000
#define TSEQ 12
#define CAP 128          // per-node CSR bucket capacity (Poisson(32), 11 sigma)
#define PADI 32          // cnt counter padding: one counter per 128-byte line

__device__ __forceinline__ void fma4(float4& acc, float a, const float4& w) {
  acc.x += a * w.x; acc.y += a * w.y; acc.z += a * w.z; acc.w += a * w.w;
}

__device__ __forceinline__ float4 h8_to_f4(uint2 v) {
  union { unsigned u; __half2 h; } a, b;
  a.u = v.x; b.u = v.y;
  float2 fa = __half22float2(a.h);
  float2 fb = __half22float2(b.h);
  return make_float4(fa.x, fa.y, fb.x, fb.y);
}

__device__ __forceinline__ uint2 f4_to_h8(float4 o) {
  union { unsigned u; __half2 h; } a, b;
  a.h = __floats2half2_rn(o.x, o.y);
  b.h = __floats2half2_rn(o.z, o.w);
  uint2 r; r.x = a.u; r.y = b.u;
  return r;
}

// ---------------- prep: zero cnt counters + all weight transposes ----------------
// blocks [0,625): cnt_pad zero
// blocks [625,1009): transposes
__global__ void k_prep(const float* __restrict__ fuse_W,
                       const float* __restrict__ gcn_W,
                       int* __restrict__ cnt_pad,
                       float* __restrict__ fuse_Wt,
                       float* __restrict__ gWt0,
                       __half* __restrict__ gWh) {
  int b = blockIdx.x;
  if (b < 625) {
    int i = b * 256 + threadIdx.x;
    ((int4*)cnt_pad)[i] = make_int4(0, 0, 0, 0);
  } else {
    int i = (b - 625) * 256 + threadIdx.x;
    if (i < 49152) {
      int k = i >> 7, d = i & 127;
      fuse_Wt[i] = fuse_W[d * 384 + k];
    } else if (i < 65536) {
      int j = i - 49152;
      int k = j >> 7, d = j & 127;
      gWt0[j] = gcn_W[d * 128 + k];
    } else if (i < 98304) {
      int j = i - 65536;
      int l = 1 + (j >> 14), jj = j & 16383;
      int k = jj >> 7, d = jj & 127;
      gWh[j] = (__half)gcn_W[l * 16384 + d * 128 + k];
    }
  }
}

// ---------------- GEMM device body: out[n][d] = sum_k A[n][k]*Wt[k][d] (+bias) ------
// KC = k-rows per LDS staging chunk (Ws holds KC*128 floats).
#define G_TN 2
#define G_BN 32   // 16 dq-groups * 2 rows

template<int KC>
__device__ __forceinline__ void gemm_body(
    float* Ws, int gb,
    const float* a0, int s0, const float* a1, int s1, const float* a2, int s2,
    int nparts, const float* Wt, const float* bias, const float* deg,
    float* outf, uint2* outh)
{
  const int t = threadIdx.x;
  const int dq = t & 15;
  const int ng = t >> 4;
  const int n_base = gb * G_BN + ng * G_TN;

  float4 acc0[G_TN], acc1[G_TN];
  #pragma unroll
  for (int i = 0; i < G_TN; ++i) {
    acc0[i] = make_float4(0.f, 0.f, 0.f, 0.f);
    acc1[i] = make_float4(0.f, 0.f, 0.f, 0.f);
  }

  for (int p = 0; p < nparts; ++p) {
    const float* ap; int as;
    if (p == 0) { ap = a0; as = s0; }
    else if (p == 1) { ap = a1; as = s1; }
    else { ap = a2; as = s2; }
    const float* rp[G_TN];
    #pragma unroll
    for (int i = 0; i < G_TN; ++i) rp[i] = ap + (size_t)(n_base + i) * as;

    for (int c = 0; c < 128 / KC; ++c) {
      const float4* wsrc = (const float4*)(Wt + (p * 128 + c * KC) * 128);
      float4* wdst = (float4*)Ws;
      #pragma unroll
      for (int it = 0; it < KC / 8; ++it) wdst[it * 256 + t] = wsrc[it * 256 + t];
      __syncthreads();

      const int ks = c * KC;
      for (int k = 0; k < KC; k += 4) {
        float4 av[G_TN];
        #pragma unroll
        for (int i = 0; i < G_TN; ++i) av[i] = *(const float4*)(rp[i] + ks + k);
        #pragma unroll
        for (int j = 0; j < 4; ++j) {
          const float4 w0 = *(const float4*)&Ws[(k + j) * 128 + 4 * dq];
          const float4 w1 = *(const float4*)&Ws[(k + j) * 128 + 64 + 4 * dq];
          #pragma unroll
          for (int i = 0; i < G_TN; ++i) {
            float a = (j == 0) ? av[i].x : (j == 1) ? av[i].y : (j == 2) ? av[i].z : av[i].w;
            fma4(acc0[i], a, w0);
            fma4(acc1[i], a, w1);
          }
        }
      }
      __syncthreads();
    }
  }

  float4 b0 = make_float4(0.f,0.f,0.f,0.f), b1 = b0;
  if (bias) {
    b0 = *(const float4*)&bias[4 * dq];
    b1 = *(const float4*)&bias[64 + 4 * dq];
  }
  #pragma unroll
  for (int i = 0; i < G_TN; ++i) {
    int r = n_base + i;
    float4 o0 = make_float4(acc0[i].x + b0.x, acc0[i].y + b0.y,
                            acc0[i].z + b0.z, acc0[i].w + b0.w);
    float4 o1 = make_float4(acc1[i].x + b1.x, acc1[i].y + b1.y,
                            acc1[i].z + b1.z, acc1[i].w + b1.w);
    if (outf) {
      *(float4*)(outf + (size_t)r * DD + 4 * dq) = o0;
      *(float4*)(outf + (size_t)r * DD + 64 + 4 * dq) = o1;
    } else {
      float di = rsqrtf(deg[r]);
      o0.x *= di; o0.y *= di; o0.z *= di; o0.w *= di;
      o1.x *= di; o1.y *= di; o1.z *= di; o1.w *= di;
      outh[(size_t)r * 32 + dq] = f4_to_h8(o0);
      outh[(size_t)r * 32 + 16 + dq] = f4_to_h8(o1);
    }
  }
}

// ---------------- mega: fuse-GEMM blocks [0,625) || edge blocks [625,3125) ----------
// r0 measured-best GEMM shape (64x128 Ws, lb(256,4)). Edge path: ONLY the
// slot-claim atomic remains; deg is computed post-hoc by k_deg from the CSR,
// removing 640k float atomics (~25-40 MB of scattered memory-side write traffic
// -- the dominant component of this kernel's ~1 TB/s scattered-traffic wall).
__global__ __launch_bounds__(256, 4) void k_mega(
    const float* __restrict__ emb, const float* __restrict__ demand,
    const float* __restrict__ supply,
    const float* __restrict__ fuse_Wt, const float* __restrict__ fuse_b,
    float* __restrict__ temp0,
    const int* __restrict__ src, const int* __restrict__ dst,
    const float* __restrict__ w,
    int* __restrict__ cnt_pad,
    uint2* __restrict__ csr)
{
  __shared__ float Ws[64 * 128];    // 32 KB (edge blocks carry it unused)
  if (blockIdx.x < 625) {
    gemm_body<64>(Ws, blockIdx.x,
                  emb, 128, demand + 11 * 128, TSEQ * 128, supply + 11 * 128, TSEQ * 128,
                  3, fuse_Wt, fuse_b, nullptr, temp0, nullptr);
  } else {
    int e = (blockIdx.x - 625) * 256 + threadIdx.x;   // exactly EE threads
    int s = src[e], d = dst[e];
    float we = w[e];
    int slot = atomicAdd(&cnt_pad[(size_t)d * PADI], 1);
    if (slot < CAP) csr[(size_t)d * CAP + slot] = make_uint2((unsigned)s, __float_as_uint(we));
  }
}

// ---------------- deg: deg[n] = 1 + sum of bucket weights (replaces deg atomics) ----
// 8 lanes per node, shuffle-reduce. CSR region is L2/L3-resident right after k_mega.
__global__ __launch_bounds__(256, 8) void k_deg(
    const int* __restrict__ cnt_pad, const uint2* __restrict__ csr,
    float* __restrict__ deg)
{
  const int t = threadIdx.x;
  const int lane = t & 7;           // 8 lanes per node
  const int ng = t >> 3;            // 32 nodes per block
  const int n = blockIdx.x * 32 + ng;
  int m = cnt_pad[(size_t)n * PADI]; if (m > CAP) m = CAP;
  const size_t base = (size_t)n * CAP;
  float s = 0.f;
  for (int j = lane; j < m; j += 8) s += __uint_as_float(csr[base + j].y);
  s += __shfl_xor(s, 1);
  s += __shfl_xor(s, 2);
  s += __shfl_xor(s, 4);
  if (lane == 0) deg[n] = 1.0f + s;
}

// ---------------- x0 GEMM: xh = rsqrt(deg)*(temp0 @ W0^T), fp16 ----------------
__global__ __launch_bounds__(256, 8) void k_gemm_x0(
    const float* __restrict__ temp0, const float* __restrict__ gWt0,
    const float* __restrict__ deg, uint2* __restrict__ outh)
{
  __shared__ float Ws[32 * 128];
  gemm_body<32>(Ws, blockIdx.x, temp0, 128, temp0, 128, temp0, 128,
                1, gWt0, nullptr, deg, nullptr, outh);
}

// ---------------- fused aggregation (+ optional next-layer GEMM) ----------------
template<bool NEXT>
__global__ __launch_bounds__(256, 6) void k_agg_fused(
    const uint2* __restrict__ xh, const float* __restrict__ tin,
    const int* __restrict__ cnt_pad, const uint2* __restrict__ csr,
    const float* __restrict__ deg, const float* __restrict__ bias,
    const uint2* __restrict__ Wh,      // fp16-packed next W, k-major [128][32 uint2]
    float* __restrict__ tout,
    uint2* __restrict__ xh_out)
{
  __shared__ float rows[NEXT ? 8 * 128 : 8];
  __shared__ uint2 Whs[NEXT ? 2048 : 8];   // 16 KB: one k=64 half of W

  const int t = threadIdx.x;
  const int dq = t & 31;          // uint2 column (4 dims)
  const int nl = t >> 5;          // 8 nodes per block
  const int n = blockIdx.x * 8 + nl;

  if constexpr (NEXT) {
    // stage first k-half early; latency hides under the gather below
    #pragma unroll
    for (int i = 0; i < 8; ++i) Whs[i * 256 + t] = Wh[i * 256 + t];
  }

  const float di = rsqrtf(deg[n]);
  float4 acc = h8_to_f4(xh[(size_t)n * 32 + dq]);   // self loop (weight 1, pre-di)

  const size_t base = (size_t)n * CAP;
  int m = cnt_pad[(size_t)n * PADI]; if (m > CAP) m = CAP;
  int j = 0;
  for (; j + 16 <= m; j += 16) {
    uint2 c[16];
    #pragma unroll
    for (int u = 0; u < 16; ++u) c[u] = csr[base + j + u];
    uint2 v[16];
    #pragma unroll
    for (int u = 0; u < 16; ++u) v[u] = xh[(size_t)c[u].x * 32 + dq];
    #pragma unroll
    for (int u = 0; u < 16; ++u) fma4(acc, __uint_as_float(c[u].y), h8_to_f4(v[u]));
  }
  for (; j + 4 <= m; j += 4) {
    uint2 c[4];
    #pragma unroll
    for (int u = 0; u < 4; ++u) c[u] = csr[base + j + u];
    uint2 v[4];
    #pragma unroll
    for (int u = 0; u < 4; ++u) v[u] = xh[(size_t)c[u].x * 32 + dq];
    #pragma unroll
    for (int u = 0; u < 4; ++u) fma4(acc, __uint_as_float(c[u].y), h8_to_f4(v[u]));
  }
  for (; j < m; ++j) {
    uint2 c = csr[base + j];
    fma4(acc, __uint_as_float(c.y), h8_to_f4(xh[(size_t)c.x * 32 + dq]));
  }

  const float4 b4 = *(const float4*)&bias[4 * dq];
  const float4 ti = ((const float4*)tin)[(size_t)n * 32 + dq];
  float4 o;
  o.x = 0.9f * (di * acc.x + b4.x) + 0.1f * ti.x;
  o.y = 0.9f * (di * acc.y + b4.y) + 0.1f * ti.y;
  o.z = 0.9f * (di * acc.z + b4.z) + 0.1f * ti.z;
  o.w = 0.9f * (di * acc.w + b4.w) + 0.1f * ti.w;
  ((float4*)tout)[(size_t)n * 32 + dq] = o;

  if constexpr (NEXT) {
    *(float4*)&rows[nl * 128 + 4 * dq] = o;
    __syncthreads();            // covers rows store + Whs half-0 staging

    float4 x = make_float4(0.f, 0.f, 0.f, 0.f);
    const float* myrow = &rows[nl * 128];
    #pragma unroll 4
    for (int k = 0; k < 64; ++k) {
      fma4(x, myrow[k], h8_to_f4(Whs[k * 32 + dq]));
    }
    __syncthreads();            // all done with half 0
    #pragma unroll
    for (int i = 0; i < 8; ++i) Whs[i * 256 + t] = Wh[2048 + i * 256 + t];
    __syncthreads();            // half 1 staged
    #pragma unroll 4
    for (int k = 0; k < 64; ++k) {
      fma4(x, myrow[64 + k], h8_to_f4(Whs[k * 32 + dq]));
    }
    x.x *= di; x.y *= di; x.z *= di; x.w *= di;
    xh_out[(size_t)n * 32 + dq] = f4_to_h8(x);
  }
}

// ---------------- launch ----------------
extern "C" void kernel_launch(void* const* d_in, const int* in_sizes, int n_in,
                              void* d_out, int out_size, void* d_ws, size_t ws_size,
                              hipStream_t stream) {
  const float* demand = (const float*)d_in[0];
  const float* supply = (const float*)d_in[1];
  const int*   eidx   = (const int*)d_in[5];
  const float* eattr  = (const float*)d_in[6];
  const float* emb    = (const float*)d_in[10];
  const float* fuse_W = (const float*)d_in[11];
  const float* fuse_b = (const float*)d_in[12];
  const float* gcn_W  = (const float*)d_in[13];
  const float* gcn_b  = (const float*)d_in[14];
  float* outp = (float*)d_out;

  char* ws = (char*)d_ws;
  size_t o = 0;
  auto alloc = [&](size_t bytes) {
    char* p = ws + o;
    o += (bytes + 255) & ~(size_t)255;
    return p;
  };
  float*  deg     = (float*)alloc((size_t)NN * 4);          // compact, 80 KB
  int*    cnt_pad = (int*)alloc((size_t)NN * PADI * 4);     // 2.56 MB
  uint2*  csr     = (uint2*)alloc((size_t)NN * CAP * 8);
  float*  fuse_Wt = (float*)alloc((size_t)384 * 128 * 4);
  float*  gWt0    = (float*)alloc((size_t)128 * 128 * 4);
  __half* gWh     = (__half*)alloc((size_t)2 * 128 * 128 * 2);
  float*  temp0   = (float*)alloc((size_t)NN * DD * 4);
  float*  temp1   = (float*)alloc((size_t)NN * DD * 4);
  uint2*  xh_a    = (uint2*)alloc((size_t)NN * DD * 2);
  uint2*  xh_b    = (uint2*)alloc((size_t)NN * DD * 2);

  const int* srcv = eidx;        // edge_index[0]
  const int* dstv = eidx + EE;   // edge_index[1]

  k_prep<<<1009, 256, 0, stream>>>(fuse_W, gcn_W, cnt_pad, fuse_Wt, gWt0, gWh);

  k_mega<<<3125, 256, 0, stream>>>(emb, demand, supply, fuse_Wt, fuse_b, temp0,
                                   srcv, dstv, eattr, cnt_pad, csr);

  k_deg<<<625, 256, 0, stream>>>(cnt_pad, csr, deg);

  k_gemm_x0<<<625, 256, 0, stream>>>(temp0, gWt0, deg, xh_a);

  const int AB = NN / 8;  // 2500
  k_agg_fused<true ><<<AB, 256, 0, stream>>>(xh_a, temp0, cnt_pad, csr, deg, gcn_b,
                                             (const uint2*)gWh, temp1, xh_b);
  k_agg_fused<true ><<<AB, 256, 0, stream>>>(xh_b, temp1, cnt_pad, csr, deg, gcn_b + 128,
                                             (const uint2*)(gWh + 16384), temp0, xh_a);
  k_agg_fused<false><<<AB, 256, 0, stream>>>(xh_a, temp0, cnt_pad, csr, deg, gcn_b + 256,
                                             nullptr, outp, nullptr);
}